// Round 1
// baseline (256.203 us; speedup 1.0000x reference)
//
#include <hip/hip_runtime.h>

// FCOS decode, level stride=8.
// Inputs:  t_ltrb [32,128,128,4] f32, center_logits [32,128,128,1] f32,
//          cls_logits [32,128,128,80] f32, img_h (unused), img_w (unused)
// Outputs (concat flat, all f32): xywh [nPix*4] | cls_idx [nPix] | conf [nPix]

#define NB   32
#define NH   128
#define NW   128
#define NC   80
#define HWPX (NH * NW)          // 16384
#define NPIX (NB * HWPX)        // 524288

__global__ __launch_bounds__(256) void fcos_decode_kernel(
    const float* __restrict__ t_ltrb,
    const float* __restrict__ center_logits,
    const float* __restrict__ cls_logits,
    float* __restrict__ out)
{
    int pix = blockIdx.x * blockDim.x + threadIdx.x;
    if (pix >= NPIX) return;

    int pimg = pix & (HWPX - 1);
    int gy = pimg >> 7;          // / NW
    int gx = pimg & (NW - 1);

    // ltrb decode: p = exp(t) * 8
    float4 t4 = reinterpret_cast<const float4*>(t_ltrb)[pix];
    float pl = __expf(t4.x) * 8.0f;
    float pt = __expf(t4.y) * 8.0f;
    float pr = __expf(t4.z) * 8.0f;
    float pb = __expf(t4.w) * 8.0f;

    float cx = ((float)gx * 8.0f + 4.0f) + (pr - pl) * 0.5f;
    float cy = ((float)gy * 8.0f + 4.0f) + (pb - pt) * 0.5f;
    float w  = pl + pr;
    float h  = pt + pb;

    // argmax over 80 class logits (sigmoid monotonic -> max on logits).
    // Strict '>' keeps first occurrence, matching np.argmax.
    const float4* cl = reinterpret_cast<const float4*>(cls_logits + (size_t)pix * NC);
    float best = -INFINITY;
    int bidx = 0;
    #pragma unroll
    for (int j = 0; j < NC / 4; ++j) {
        float4 v = cl[j];
        if (v.x > best) { best = v.x; bidx = j * 4 + 0; }
        if (v.y > best) { best = v.y; bidx = j * 4 + 1; }
        if (v.z > best) { best = v.z; bidx = j * 4 + 2; }
        if (v.w > best) { best = v.w; bidx = j * 4 + 3; }
    }

    float pc = 1.0f / (1.0f + __expf(-center_logits[pix]));
    float ps = 1.0f / (1.0f + __expf(-best));
    float conf = sqrtf(pc * ps);

    reinterpret_cast<float4*>(out)[pix] = make_float4(cx, cy, w, h);
    out[(size_t)4 * NPIX + pix] = (float)bidx;
    out[(size_t)5 * NPIX + pix] = conf;
}

extern "C" void kernel_launch(void* const* d_in, const int* in_sizes, int n_in,
                              void* d_out, int out_size, void* d_ws, size_t ws_size,
                              hipStream_t stream) {
    const float* t_ltrb        = (const float*)d_in[0];
    const float* center_logits = (const float*)d_in[1];
    const float* cls_logits    = (const float*)d_in[2];
    float* out = (float*)d_out;

    int threads = 256;
    int blocks = (NPIX + threads - 1) / threads;  // 2048
    fcos_decode_kernel<<<blocks, threads, 0, stream>>>(t_ltrb, center_logits, cls_logits, out);
}

// Round 2
// 241.961 us; speedup vs baseline: 1.0589x; 1.0589x over previous
//
#include <hip/hip_runtime.h>

// FCOS decode, level stride=8.
// Inputs:  t_ltrb [32,128,128,4] f32, center_logits [32,128,128,1] f32,
//          cls_logits [32,128,128,80] f32, img_h (unused), img_w (unused)
// Outputs (concat flat, all f32): xywh [nPix*4] | cls_idx [nPix] | conf [nPix]
//
// 4 lanes per pixel: lane l reads float4 k*4+l of the pixel's 20 float4s of
// class logits -> each 4-lane group covers a contiguous 64B-aligned segment
// per k, so every wave-load is fully coalesced (16 used lines / instr).
// Group leaders (every 4th lane) are consecutive pixels -> their scalar/f4
// accesses to ltrb/center/outputs are consecutive addresses (coalesced too).

#define NB   32
#define NH   128
#define NW   128
#define NC   80
#define HWPX (NH * NW)          // 16384
#define NPIX (NB * HWPX)        // 524288

__global__ __launch_bounds__(256) void fcos_decode_kernel(
    const float* __restrict__ t_ltrb,
    const float* __restrict__ center_logits,
    const float* __restrict__ cls_logits,
    float* __restrict__ out)
{
    int tid = blockIdx.x * blockDim.x + threadIdx.x;
    int pix = tid >> 2;        // 4 lanes per pixel
    int l   = tid & 3;
    if (pix >= NPIX) return;

    // ---- argmax over 80 class logits (sigmoid monotonic -> max on logits) ----
    const float4* cp = reinterpret_cast<const float4*>(cls_logits + (size_t)pix * NC);
    float best = -INFINITY;
    int bidx = 0;
    #pragma unroll
    for (int k = 0; k < 5; ++k) {
        float4 v = cp[k * 4 + l];          // classes k*16 + l*4 .. +3
        int c = k * 16 + l * 4;
        if (v.x > best) { best = v.x; bidx = c + 0; }
        if (v.y > best) { best = v.y; bidx = c + 1; }
        if (v.z > best) { best = v.z; bidx = c + 2; }
        if (v.w > best) { best = v.w; bidx = c + 3; }
    }
    // reduce across the 4 lanes of the group; smaller index wins ties
    // (matches np.argmax first-occurrence)
    #pragma unroll
    for (int m = 2; m >= 1; m >>= 1) {
        float ov = __shfl_xor(best, m, 4);
        int   oi = __shfl_xor(bidx, m, 4);
        if (ov > best || (ov == best && oi < bidx)) { best = ov; bidx = oi; }
    }

    if (l == 0) {
        int pimg = pix & (HWPX - 1);
        int gy = pimg >> 7;          // / NW
        int gx = pimg & (NW - 1);

        // ltrb decode: p = exp(t) * 8
        float4 t4 = reinterpret_cast<const float4*>(t_ltrb)[pix];
        float pl = __expf(t4.x) * 8.0f;
        float pt = __expf(t4.y) * 8.0f;
        float pr = __expf(t4.z) * 8.0f;
        float pb = __expf(t4.w) * 8.0f;

        float cx = ((float)gx * 8.0f + 4.0f) + (pr - pl) * 0.5f;
        float cy = ((float)gy * 8.0f + 4.0f) + (pb - pt) * 0.5f;
        float w  = pl + pr;
        float h  = pt + pb;

        float pc = 1.0f / (1.0f + __expf(-center_logits[pix]));
        float ps = 1.0f / (1.0f + __expf(-best));
        float conf = sqrtf(pc * ps);

        reinterpret_cast<float4*>(out)[pix] = make_float4(cx, cy, w, h);
        out[(size_t)4 * NPIX + pix] = (float)bidx;
        out[(size_t)5 * NPIX + pix] = conf;
    }
}

extern "C" void kernel_launch(void* const* d_in, const int* in_sizes, int n_in,
                              void* d_out, int out_size, void* d_ws, size_t ws_size,
                              hipStream_t stream) {
    const float* t_ltrb        = (const float*)d_in[0];
    const float* center_logits = (const float*)d_in[1];
    const float* cls_logits    = (const float*)d_in[2];
    float* out = (float*)d_out;

    int threads = 256;
    int total_threads = NPIX * 4;                      // 4 lanes per pixel
    int blocks = (total_threads + threads - 1) / threads;  // 8192
    fcos_decode_kernel<<<blocks, threads, 0, stream>>>(t_ltrb, center_logits, cls_logits, out);
}

// Round 3
// 239.225 us; speedup vs baseline: 1.0710x; 1.0114x over previous
//
#include <hip/hip_runtime.h>

// FCOS decode, level stride=8.
// Inputs:  t_ltrb [32,128,128,4] f32, center_logits [32,128,128,1] f32,
//          cls_logits [32,128,128,80] f32, img_h (unused), img_w (unused)
// Outputs (concat flat, all f32): xywh [nPix*4] | cls_idx [nPix] | conf [nPix]
//
// 4 lanes per *pair* of pixels: lane l issues 10 independent nontemporal
// float4 loads (5 per pixel), each 4-lane group covering full 64B-aligned
// segments -> fully coalesced wave loads, 10 loads in flight per lane.
// All traffic is single-use -> nontemporal (nt) loads/stores to avoid
// L2/L3 pollution. Leaders (every 4th lane, consecutive pixel pairs)
// do the ltrb/center decode and the (coalesced) output stores.

#define NB   32
#define NH   128
#define NW   128
#define NC   80
#define HWPX (NH * NW)          // 16384
#define NPIX (NB * HWPX)        // 524288

typedef float f4 __attribute__((ext_vector_type(4)));

__device__ __forceinline__ float fast_sigmoid(float x) {
    return 1.0f / (1.0f + __expf(-x));
}

__global__ __launch_bounds__(256) void fcos_decode_kernel(
    const float* __restrict__ t_ltrb,
    const float* __restrict__ center_logits,
    const float* __restrict__ cls_logits,
    float* __restrict__ out)
{
    int tid = blockIdx.x * blockDim.x + threadIdx.x;
    int grp = tid >> 2;          // each 4-lane group handles 2 pixels
    int l   = tid & 3;
    int p0  = grp * 2;
    if (p0 >= NPIX) return;

    const f4* cp0 = reinterpret_cast<const f4*>(cls_logits) + (size_t)p0 * (NC / 4);
    const f4* cp1 = cp0 + (NC / 4);

    // Issue all 10 independent loads up front (nontemporal: zero reuse).
    f4 va[5], vb[5];
    #pragma unroll
    for (int k = 0; k < 5; ++k) va[k] = __builtin_nontemporal_load(&cp0[k * 4 + l]);
    #pragma unroll
    for (int k = 0; k < 5; ++k) vb[k] = __builtin_nontemporal_load(&cp1[k * 4 + l]);

    // Per-lane argmax (sigmoid monotonic -> argmax on raw logits; strict '>'
    // + ascending index = first occurrence, matching np.argmax).
    float b0 = -INFINITY, b1 = -INFINITY;
    int i0 = 0, i1 = 0;
    #pragma unroll
    for (int k = 0; k < 5; ++k) {
        int c = k * 16 + l * 4;
        f4 v = va[k];
        if (v.x > b0) { b0 = v.x; i0 = c + 0; }
        if (v.y > b0) { b0 = v.y; i0 = c + 1; }
        if (v.z > b0) { b0 = v.z; i0 = c + 2; }
        if (v.w > b0) { b0 = v.w; i0 = c + 3; }
        f4 w = vb[k];
        if (w.x > b1) { b1 = w.x; i1 = c + 0; }
        if (w.y > b1) { b1 = w.y; i1 = c + 1; }
        if (w.z > b1) { b1 = w.z; i1 = c + 2; }
        if (w.w > b1) { b1 = w.w; i1 = c + 3; }
    }
    // Cross-lane reduce over the 4-lane group; smaller index wins ties.
    #pragma unroll
    for (int m = 2; m >= 1; m >>= 1) {
        float ov0 = __shfl_xor(b0, m, 4);
        int   oi0 = __shfl_xor(i0, m, 4);
        if (ov0 > b0 || (ov0 == b0 && oi0 < i0)) { b0 = ov0; i0 = oi0; }
        float ov1 = __shfl_xor(b1, m, 4);
        int   oi1 = __shfl_xor(i1, m, 4);
        if (ov1 > b1 || (ov1 == b1 && oi1 < i1)) { b1 = ov1; i1 = oi1; }
    }

    if (l == 0) {
        const f4* lt = reinterpret_cast<const f4*>(t_ltrb);
        f4 t0 = __builtin_nontemporal_load(&lt[p0]);
        f4 t1 = __builtin_nontemporal_load(&lt[p0 + 1]);
        float c0 = __builtin_nontemporal_load(&center_logits[p0]);
        float c1 = __builtin_nontemporal_load(&center_logits[p0 + 1]);

        #pragma unroll
        for (int j = 0; j < 2; ++j) {
            int pix = p0 + j;
            f4 t4 = j ? t1 : t0;
            float cl_ = j ? c1 : c0;
            float bv  = j ? b1 : b0;
            int   bi  = j ? i1 : i0;

            int pimg = pix & (HWPX - 1);
            int gy = pimg >> 7;
            int gx = pimg & (NW - 1);

            float pl = __expf(t4.x) * 8.0f;
            float pt = __expf(t4.y) * 8.0f;
            float pr = __expf(t4.z) * 8.0f;
            float pb = __expf(t4.w) * 8.0f;

            f4 r;
            r.x = ((float)gx * 8.0f + 4.0f) + (pr - pl) * 0.5f;  // cx
            r.y = ((float)gy * 8.0f + 4.0f) + (pb - pt) * 0.5f;  // cy
            r.z = pl + pr;                                        // w
            r.w = pt + pb;                                        // h

            float conf = sqrtf(fast_sigmoid(cl_) * fast_sigmoid(bv));

            __builtin_nontemporal_store(r, reinterpret_cast<f4*>(out) + pix);
            __builtin_nontemporal_store((float)bi, out + (size_t)4 * NPIX + pix);
            __builtin_nontemporal_store(conf, out + (size_t)5 * NPIX + pix);
        }
    }
}

extern "C" void kernel_launch(void* const* d_in, const int* in_sizes, int n_in,
                              void* d_out, int out_size, void* d_ws, size_t ws_size,
                              hipStream_t stream) {
    const float* t_ltrb        = (const float*)d_in[0];
    const float* center_logits = (const float*)d_in[1];
    const float* cls_logits    = (const float*)d_in[2];
    float* out = (float*)d_out;

    int threads = 256;
    long long total_threads = (long long)(NPIX / 2) * 4;   // 4 lanes per 2 pixels
    int blocks = (int)((total_threads + threads - 1) / threads);  // 4096
    fcos_decode_kernel<<<blocks, threads, 0, stream>>>(t_ltrb, center_logits, cls_logits, out);
}